// Round 4
// baseline (481.905 us; speedup 1.0000x reference)
//
#include <hip/hip_runtime.h>
#include <hip/hip_bf16.h>
#include <math.h>

#define N_NODES 50000
#define E_EDGES 800000
#define IN_DIM  128
#define HID     64
#define KF      4
#define EXP_HID 64

// d_out layout (float32, concatenated in return order):
//   disen_graph_emb (K*HID = 256) | Z (N*K*HID = 12,800,000) |
//   e_h_final (E = 800,000)       | e_h_all (K*E = 3,200,000)
#define OFF_DISEN 0
#define OFF_Z     (KF*HID)
#define OFF_EHF   (OFF_Z + N_NODES*KF*HID)
#define OFF_EHALL (OFF_EHF + E_EDGES)

#define NPB2 16                  // nodes per block (50000 = 3125 * 16, exact)
#define NROWS (N_NODES * KF)     // 200000 (n,k) rows
#define PQ_ELEMS ((size_t)NROWS * EXP_HID)   // 12.8M elems each (bf16)

// ---------------------------------------------------------------------------
// disen init: harness poisons d_out once; rewrite the 256-float region every
// call before the fused kernel's atomics.
// ---------------------------------------------------------------------------
__global__ void disen_init_kernel(float* __restrict__ disen) {
  disen[threadIdx.x] = 0.f;
}

// ---------------------------------------------------------------------------
// Fused node-side kernel. 3125 blocks x 256 threads, 16 nodes/block.
// Phase 1 (thread = (k,h)): Z[n,k,h] = relu(x.W_init+b), row-normalize,
//   write Z to d_out, fold disen-max in registers (1 atomicMax/thread),
//   stage normalized Z in LDS tile zt[64 rows][64 h].
// Phase 2 (thread = (wave, o)): P/Q rows from zt broadcasts x W1 columns
//   held in 128 VGPRs; store bf16.
// ---------------------------------------------------------------------------
__global__ __launch_bounds__(256) void fused_zpq_kernel(
    const float* __restrict__ x, const float* __restrict__ W,
    const float* __restrict__ b, const float* __restrict__ W1,
    const float* __restrict__ b1, float* __restrict__ out,
    unsigned short* __restrict__ P, unsigned short* __restrict__ Q) {
  __shared__ __align__(16) float xs[NPB2 * IN_DIM];    // 8 KB
  __shared__ __align__(16) float zt[NPB2 * KF * HID];  // 16 KB
  const int tid = threadIdx.x;
  const int n0 = blockIdx.x * NPB2;

  // stage 16 x-rows (2048 floats) as 2x256 float4 loads
  ((float4*)xs)[tid]       = ((const float4*)(x + (size_t)n0 * IN_DIM))[tid];
  ((float4*)xs)[tid + 256] = ((const float4*)(x + (size_t)n0 * IN_DIM))[tid + 256];
  __syncthreads();

  const int k = tid >> 6;
  const int h = tid & 63;

  // ---- phase 1: Z ----
  const float bias = b[k * HID + h];
  float acc[NPB2];
#pragma unroll
  for (int j = 0; j < NPB2; ++j) acc[j] = bias;

  const float* wp = W + k * IN_DIM * HID + h;   // coalesced over h
#pragma unroll 2
  for (int i4 = 0; i4 < IN_DIM / 4; ++i4) {
    const float w0 = wp[(i4 * 4 + 0) * HID];
    const float w1 = wp[(i4 * 4 + 1) * HID];
    const float w2 = wp[(i4 * 4 + 2) * HID];
    const float w3 = wp[(i4 * 4 + 3) * HID];
#pragma unroll
    for (int j = 0; j < NPB2; ++j) {
      const float4 xv = ((const float4*)(xs + j * IN_DIM))[i4];  // broadcast
      acc[j] = fmaf(xv.x, w0, acc[j]);
      acc[j] = fmaf(xv.y, w1, acc[j]);
      acc[j] = fmaf(xv.z, w2, acc[j]);
      acc[j] = fmaf(xv.w, w3, acc[j]);
    }
  }

  float dmax = 0.f;
#pragma unroll
  for (int j = 0; j < NPB2; ++j) {
    float z = fmaxf(acc[j], 0.f);
    float s = z * z;
#pragma unroll
    for (int d = 1; d < 64; d <<= 1) s += __shfl_xor(s, d, 64);
    const float zn = z / fmaxf(sqrtf(s), 1e-12f);
    out[OFF_Z + (size_t)(n0 + j) * (KF * HID) + k * HID + h] = zn;
    zt[(j * KF + k) * HID + h] = zn;
    dmax = fmaxf(dmax, zn);
  }
  // Z >= 0: uint-punned atomicMax is exact, order-independent (3125/addr)
  atomicMax((unsigned int*)(out + OFF_DISEN + tid), __float_as_uint(dmax));
  __syncthreads();

  // ---- phase 2: P/Q ----
  const int lane = h;   // output channel o
  float ws[HID], wd[HID];
#pragma unroll
  for (int hh = 0; hh < HID; ++hh) {
    ws[hh] = W1[hh * EXP_HID + lane];              // coalesced, L2-broadcast
    wd[hh] = W1[(HID + hh) * EXP_HID + lane];
  }
  const float bb = b1[lane];

#pragma unroll 2
  for (int r = 0; r < 16; ++r) {
    const int row = k * 16 + r;                    // wave k owns rows [16k,16k+16)
    float accP = bb, accQ = 0.f;
    const float4* z4 = (const float4*)(zt + row * HID);
#pragma unroll
    for (int h4 = 0; h4 < 16; ++h4) {
      const float4 z = z4[h4];                     // uniform broadcast
      accP = fmaf(z.x, ws[h4 * 4 + 0], accP);
      accQ = fmaf(z.x, wd[h4 * 4 + 0], accQ);
      accP = fmaf(z.y, ws[h4 * 4 + 1], accP);
      accQ = fmaf(z.y, wd[h4 * 4 + 1], accQ);
      accP = fmaf(z.z, ws[h4 * 4 + 2], accP);
      accQ = fmaf(z.z, wd[h4 * 4 + 2], accQ);
      accP = fmaf(z.w, ws[h4 * 4 + 3], accP);
      accQ = fmaf(z.w, wd[h4 * 4 + 3], accQ);
    }
    const size_t orow = ((size_t)n0 * KF + row) * EXP_HID + lane;
    __hip_bfloat16 hp = __float2bfloat16(accP);    // RNE
    __hip_bfloat16 hq = __float2bfloat16(accQ);
    P[orow] = *(unsigned short*)&hp;
    Q[orow] = *(unsigned short*)&hq;
  }
}

// ---------------------------------------------------------------------------
// Edge kernel: one thread per (edge,k):
//   ek = W2 . relu(bf16(P[src,k,:]) + bf16(Q[dst,k,:])) + b2
// 8+8 uint4 gathers per thread; bf16 unpack = 2 exact bit-ops per pair.
// ---------------------------------------------------------------------------
__global__ __launch_bounds__(256) void edge_kernel3(
    const int* __restrict__ ei, const float* __restrict__ W2,
    const float* __restrict__ b2, const unsigned short* __restrict__ P,
    const unsigned short* __restrict__ Q, float* __restrict__ ehf,
    float* __restrict__ ehall) {
  __shared__ __align__(16) float w2s[EXP_HID];
  const int tid = threadIdx.x;
  if (tid < EXP_HID) w2s[tid] = W2[tid];
  __syncthreads();

  const int gid = blockIdx.x * 256 + tid;        // [0, E*K)
  const int e = gid >> 2;
  const int k = gid & 3;
  const int src = ei[e];
  const int dst = ei[E_EDGES + e];

  const uint4* p4 = (const uint4*)(P + ((size_t)src * KF + k) * EXP_HID);
  const uint4* q4 = (const uint4*)(Q + ((size_t)dst * KF + k) * EXP_HID);

  uint4 pv[8], qv[8];
#pragma unroll
  for (int i = 0; i < 8; ++i) pv[i] = p4[i];     // 128B contiguous per row
#pragma unroll
  for (int i = 0; i < 8; ++i) qv[i] = q4[i];

  float acc = b2[0];
#pragma unroll
  for (int i = 0; i < 8; ++i) {
    const unsigned int* pu = (const unsigned int*)&pv[i];
    const unsigned int* qu = (const unsigned int*)&qv[i];
#pragma unroll
    for (int j = 0; j < 4; ++j) {
      const unsigned int up = pu[j], uq = qu[j];
      const float p0 = __uint_as_float(up << 16);           // exact
      const float p1 = __uint_as_float(up & 0xffff0000u);   // exact
      const float q0 = __uint_as_float(uq << 16);
      const float q1 = __uint_as_float(uq & 0xffff0000u);
      const int o = i * 8 + j * 2;
      acc = fmaf(fmaxf(p0 + q0, 0.f), w2s[o], acc);     // broadcast LDS
      acc = fmaf(fmaxf(p1 + q1, 0.f), w2s[o + 1], acc);
    }
  }

  ehall[(size_t)k * E_EDGES + e] = acc;

  float m = fmaxf(acc, __shfl_xor(acc, 1, 64));
  m = fmaxf(m, __shfl_xor(m, 2, 64));
  if (k == 0) ehf[e] = m;
}

// ---------------------------------------------------------------------------
extern "C" void kernel_launch(void* const* d_in, const int* in_sizes, int n_in,
                              void* d_out, int out_size, void* d_ws,
                              size_t ws_size, hipStream_t stream) {
  const float* x      = (const float*)d_in[0];
  const int*   ei     = (const int*)  d_in[1];
  const float* W_init = (const float*)d_in[2];
  const float* b_init = (const float*)d_in[3];
  const float* W1     = (const float*)d_in[4];
  const float* b1     = (const float*)d_in[5];
  const float* W2     = (const float*)d_in[6];
  const float* b2     = (const float*)d_in[7];
  float* out = (float*)d_out;

  unsigned short* P = (unsigned short*)d_ws;     // ws >= 51.2MB (verified r2/r3)
  unsigned short* Q = P + PQ_ELEMS;

  disen_init_kernel<<<1, KF * HID, 0, stream>>>(out + OFF_DISEN);
  fused_zpq_kernel<<<N_NODES / NPB2, 256, 0, stream>>>(
      x, W_init, b_init, W1, b1, out, P, Q);
  edge_kernel3<<<(E_EDGES * KF) / 256, 256, 0, stream>>>(
      ei, W2, b2, P, Q, out + OFF_EHF, out + OFF_EHALL);
}

// Round 5
// 309.054 us; speedup vs baseline: 1.5593x; 1.5593x over previous
//
#include <hip/hip_runtime.h>
#include <hip/hip_bf16.h>
#include <math.h>

#define N_NODES 50000
#define E_EDGES 800000
#define IN_DIM  128
#define HID     64
#define KF      4
#define EXP_HID 64

// d_out layout (float32, concatenated in return order):
//   disen_graph_emb (K*HID = 256) | Z (N*K*HID = 12,800,000) |
//   e_h_final (E = 800,000)       | e_h_all (K*E = 3,200,000)
#define OFF_DISEN 0
#define OFF_Z     (KF*HID)
#define OFF_EHF   (OFF_Z + N_NODES*KF*HID)
#define OFF_EHALL (OFF_EHF + E_EDGES)

#define NPB3 32                  // nodes per block in z_kernel2 (8 per wave)
#define NROWS (N_NODES * KF)     // 200000 (n,k) rows
#define PQ_ELEMS ((size_t)NROWS * EXP_HID)   // 12.8M elems each (bf16)

// ---------------------------------------------------------------------------
// disen init: d_out is poisoned once by the harness; rewrite the 256-float
// region every call before z_kernel2's atomics.
// ---------------------------------------------------------------------------
__global__ void disen_init_kernel(float* __restrict__ disen) {
  disen[threadIdx.x] = 0.f;
}

// ---------------------------------------------------------------------------
// Kernel 1 (v2): Z[n,k,h] = relu(x.W_init+b), row-normalized; disen-max
// folded in. Partition: wave owns 8 nodes, lane = h, thread holds ALL 4 k
// (acc[8][4]) so each x ds_read_b128 broadcast feeds 16 FMAs (4x fewer LDS
// instrs than r3 — that pipe was the 125us bottleneck). W streamed from
// global (128KB, L2-resident), 16 coalesced dwords per iter.
// ---------------------------------------------------------------------------
__global__ __launch_bounds__(256) void z_kernel2(
    const float* __restrict__ x, const float* __restrict__ W,
    const float* __restrict__ b, float* __restrict__ out) {
  __shared__ __align__(16) float xs[NPB3 * IN_DIM];   // 16 KB
  __shared__ float dred[4][KF][64];                   // 4 KB
  const int tid = threadIdx.x;
  const int w = tid >> 6;
  const int lane = tid & 63;
  const int n0 = blockIdx.x * NPB3;

  // stage 32 x-rows (4096 floats) as 4x256 float4 loads; clamp tail rows
  // (clamped rows recompute row N-1 exactly -> harmless for max, stores
  // are guarded below)
#pragma unroll
  for (int t = 0; t < 4; ++t) {
    const int idx = t * 256 + tid;
    const int row = idx >> 5;                         // 32 float4 per row
    const int col4 = idx & 31;
    const int nr = min(n0 + row, N_NODES - 1);
    ((float4*)xs)[idx] = ((const float4*)(x + (size_t)nr * IN_DIM))[col4];
  }
  __syncthreads();

  float acc[8][KF];
#pragma unroll
  for (int j = 0; j < 8; ++j)
#pragma unroll
    for (int k = 0; k < KF; ++k) acc[j][k] = b[k * HID + lane];

  const float* wp = W + lane;                         // W[k][i][h=lane]
#pragma unroll 2
  for (int i4 = 0; i4 < IN_DIM / 4; ++i4) {
    float wv[KF][4];
#pragma unroll
    for (int k = 0; k < KF; ++k)
#pragma unroll
      for (int i = 0; i < 4; ++i)
        wv[k][i] = wp[(k * IN_DIM + i4 * 4 + i) * HID];   // coalesced, L2
#pragma unroll
    for (int j = 0; j < 8; ++j) {
      const float4 xv = ((const float4*)(xs + (w * 8 + j) * IN_DIM))[i4];
#pragma unroll
      for (int k = 0; k < KF; ++k) {
        acc[j][k] = fmaf(xv.x, wv[k][0], acc[j][k]);
        acc[j][k] = fmaf(xv.y, wv[k][1], acc[j][k]);
        acc[j][k] = fmaf(xv.z, wv[k][2], acc[j][k]);
        acc[j][k] = fmaf(xv.w, wv[k][3], acc[j][k]);
      }
    }
  }

  float dmax[KF];
#pragma unroll
  for (int k = 0; k < KF; ++k) dmax[k] = 0.f;

#pragma unroll
  for (int j = 0; j < 8; ++j) {
    const int node = n0 + w * 8 + j;
#pragma unroll
    for (int k = 0; k < KF; ++k) {
      float z = fmaxf(acc[j][k], 0.f);
      float s = z * z;
#pragma unroll
      for (int d = 1; d < 64; d <<= 1) s += __shfl_xor(s, d, 64);
      const float zn = z / fmaxf(sqrtf(s), 1e-12f);
      if (node < N_NODES)
        out[OFF_Z + (size_t)node * (KF * HID) + k * HID + lane] = zn;
      dmax[k] = fmaxf(dmax[k], zn);   // clamped rows duplicate row N-1: ok
    }
  }

  // cross-wave reduce -> one atomicMax per (k,h) per block (Z>=0: uint pun
  // is exact & order-independent)
#pragma unroll
  for (int k = 0; k < KF; ++k) dred[w][k][lane] = dmax[k];
  __syncthreads();
  {
    const int k = tid >> 6;
    const float m = fmaxf(fmaxf(dred[0][k][lane], dred[1][k][lane]),
                          fmaxf(dred[2][k][lane], dred[3][k][lane]));
    atomicMax((unsigned int*)(out + OFF_DISEN + tid), __float_as_uint(m));
  }
}

// ---------------------------------------------------------------------------
// Kernel 2: P[n,k,o] = b1[o] + sum_h Z[n,k,h] W1s[h,o]   (stored bf16)
//           Q[n,k,o] =         sum_h Z[n,k,h] W1d[h,o]   (stored bf16)
// Unchanged from round 3 (measured ~25-30us).
// ---------------------------------------------------------------------------
__global__ __launch_bounds__(256) void pq_kernel(
    const float* __restrict__ Z, const float* __restrict__ W1,
    const float* __restrict__ b1, unsigned short* __restrict__ P,
    unsigned short* __restrict__ Q) {
  __shared__ __align__(16) float zt[16 * HID];
  const int tid = threadIdx.x;
  const int lane = tid & 63;
  const int w = tid >> 6;

  float ws[HID], wd[HID];
#pragma unroll
  for (int h = 0; h < HID; ++h) {
    ws[h] = W1[h * EXP_HID + lane];
    wd[h] = W1[(HID + h) * EXP_HID + lane];
  }
  const float bb = b1[lane];

  const int rpb = NROWS / gridDim.x;             // 64 rows per block
  const int base = blockIdx.x * rpb;
  for (int t = 0; t < rpb; t += 16) {
    __syncthreads();
    ((float4*)zt)[tid] = ((const float4*)(Z + (size_t)(base + t) * HID))[tid];
    __syncthreads();
#pragma unroll
    for (int r = 0; r < 4; ++r) {
      const int row = w * 4 + r;
      float accP = bb, accQ = 0.f;
      const float4* z4 = (const float4*)(zt + row * HID);
#pragma unroll
      for (int h4 = 0; h4 < 16; ++h4) {
        const float4 z = z4[h4];
        accP = fmaf(z.x, ws[h4 * 4 + 0], accP);
        accQ = fmaf(z.x, wd[h4 * 4 + 0], accQ);
        accP = fmaf(z.y, ws[h4 * 4 + 1], accP);
        accQ = fmaf(z.y, wd[h4 * 4 + 1], accQ);
        accP = fmaf(z.z, ws[h4 * 4 + 2], accP);
        accQ = fmaf(z.z, wd[h4 * 4 + 2], accQ);
        accP = fmaf(z.w, ws[h4 * 4 + 3], accP);
        accQ = fmaf(z.w, wd[h4 * 4 + 3], accQ);
      }
      const size_t orow = (size_t)(base + t + row) * EXP_HID + lane;
      __hip_bfloat16 hp = __float2bfloat16(accP);   // RNE
      __hip_bfloat16 hq = __float2bfloat16(accQ);
      P[orow] = *(unsigned short*)&hp;
      Q[orow] = *(unsigned short*)&hq;
    }
  }
}

// ---------------------------------------------------------------------------
// Kernel 3: one thread per (edge,k):
//   ek = W2 . relu(bf16(P[src,k,:]) + bf16(Q[dst,k,:])) + b2
// Unchanged from round 3 (measured 175us, scatter-BW bound).
// ---------------------------------------------------------------------------
__global__ __launch_bounds__(256) void edge_kernel3(
    const int* __restrict__ ei, const float* __restrict__ W2,
    const float* __restrict__ b2, const unsigned short* __restrict__ P,
    const unsigned short* __restrict__ Q, float* __restrict__ ehf,
    float* __restrict__ ehall) {
  __shared__ __align__(16) float w2s[EXP_HID];
  const int tid = threadIdx.x;
  if (tid < EXP_HID) w2s[tid] = W2[tid];
  __syncthreads();

  const int gid = blockIdx.x * 256 + tid;        // [0, E*K)
  const int e = gid >> 2;
  const int k = gid & 3;
  const int src = ei[e];
  const int dst = ei[E_EDGES + e];

  const uint4* p4 = (const uint4*)(P + ((size_t)src * KF + k) * EXP_HID);
  const uint4* q4 = (const uint4*)(Q + ((size_t)dst * KF + k) * EXP_HID);

  uint4 pv[8], qv[8];
#pragma unroll
  for (int i = 0; i < 8; ++i) pv[i] = p4[i];
#pragma unroll
  for (int i = 0; i < 8; ++i) qv[i] = q4[i];

  float acc = b2[0];
#pragma unroll
  for (int i = 0; i < 8; ++i) {
    const unsigned int* pu = (const unsigned int*)&pv[i];
    const unsigned int* qu = (const unsigned int*)&qv[i];
#pragma unroll
    for (int j = 0; j < 4; ++j) {
      const unsigned int up = pu[j], uq = qu[j];
      const float p0 = __uint_as_float(up << 16);           // exact
      const float p1 = __uint_as_float(up & 0xffff0000u);   // exact
      const float q0 = __uint_as_float(uq << 16);
      const float q1 = __uint_as_float(uq & 0xffff0000u);
      const int o = i * 8 + j * 2;
      acc = fmaf(fmaxf(p0 + q0, 0.f), w2s[o], acc);
      acc = fmaf(fmaxf(p1 + q1, 0.f), w2s[o + 1], acc);
    }
  }

  ehall[(size_t)k * E_EDGES + e] = acc;

  float m = fmaxf(acc, __shfl_xor(acc, 1, 64));
  m = fmaxf(m, __shfl_xor(m, 2, 64));
  if (k == 0) ehf[e] = m;
}

// ---------------------------------------------------------------------------
extern "C" void kernel_launch(void* const* d_in, const int* in_sizes, int n_in,
                              void* d_out, int out_size, void* d_ws,
                              size_t ws_size, hipStream_t stream) {
  const float* x      = (const float*)d_in[0];
  const int*   ei     = (const int*)  d_in[1];
  const float* W_init = (const float*)d_in[2];
  const float* b_init = (const float*)d_in[3];
  const float* W1     = (const float*)d_in[4];
  const float* b1     = (const float*)d_in[5];
  const float* W2     = (const float*)d_in[6];
  const float* b2     = (const float*)d_in[7];
  float* out = (float*)d_out;

  unsigned short* P = (unsigned short*)d_ws;     // ws >= 51.2MB (verified)
  unsigned short* Q = P + PQ_ELEMS;

  disen_init_kernel<<<1, KF * HID, 0, stream>>>(out + OFF_DISEN);
  z_kernel2<<<(N_NODES + NPB3 - 1) / NPB3, 256, 0, stream>>>(
      x, W_init, b_init, out);
  pq_kernel<<<3125, 256, 0, stream>>>(out + OFF_Z, W1, b1, P, Q);
  edge_kernel3<<<(E_EDGES * KF) / 256, 256, 0, stream>>>(
      ei, W2, b2, P, Q, out + OFF_EHF, out + OFF_EHALL);
}

// Round 6
// 251.054 us; speedup vs baseline: 1.9195x; 1.2310x over previous
//
#include <hip/hip_runtime.h>
#include <hip/hip_bf16.h>
#include <math.h>

#define N_NODES 50000
#define E_EDGES 800000
#define IN_DIM  128
#define HID     64
#define KF      4
#define EXP_HID 64

// d_out layout (float32, concatenated in return order):
//   disen_graph_emb (K*HID = 256) | Z (N*K*HID = 12,800,000) |
//   e_h_final (E = 800,000)       | e_h_all (K*E = 3,200,000)
#define OFF_DISEN 0
#define OFF_Z     (KF*HID)
#define OFF_EHF   (OFF_Z + N_NODES*KF*HID)
#define OFF_EHALL (OFF_EHF + E_EDGES)

#define NPB3 32                  // nodes per block in z_kernel2 (8 per wave)
#define NROWS (N_NODES * KF)     // 200000 (n,k) rows
#define PQ_ELEMS ((size_t)NROWS * EXP_HID)   // 12.8M elems each (bf16)
#define EPW 64                   // edges per wave in edge_kernel4

// ---------------------------------------------------------------------------
__global__ void disen_init_kernel(float* __restrict__ disen) {
  disen[threadIdx.x] = 0.f;
}

// ---------------------------------------------------------------------------
// Kernel 1 (v2, unchanged from r5): Z + row-normalize + folded disen-max.
// ---------------------------------------------------------------------------
__global__ __launch_bounds__(256) void z_kernel2(
    const float* __restrict__ x, const float* __restrict__ W,
    const float* __restrict__ b, float* __restrict__ out) {
  __shared__ __align__(16) float xs[NPB3 * IN_DIM];   // 16 KB
  __shared__ float dred[4][KF][64];                   // 4 KB
  const int tid = threadIdx.x;
  const int w = tid >> 6;
  const int lane = tid & 63;
  const int n0 = blockIdx.x * NPB3;

#pragma unroll
  for (int t = 0; t < 4; ++t) {
    const int idx = t * 256 + tid;
    const int row = idx >> 5;
    const int col4 = idx & 31;
    const int nr = min(n0 + row, N_NODES - 1);
    ((float4*)xs)[idx] = ((const float4*)(x + (size_t)nr * IN_DIM))[col4];
  }
  __syncthreads();

  float acc[8][KF];
#pragma unroll
  for (int j = 0; j < 8; ++j)
#pragma unroll
    for (int k = 0; k < KF; ++k) acc[j][k] = b[k * HID + lane];

  const float* wp = W + lane;
#pragma unroll 2
  for (int i4 = 0; i4 < IN_DIM / 4; ++i4) {
    float wv[KF][4];
#pragma unroll
    for (int k = 0; k < KF; ++k)
#pragma unroll
      for (int i = 0; i < 4; ++i)
        wv[k][i] = wp[(k * IN_DIM + i4 * 4 + i) * HID];
#pragma unroll
    for (int j = 0; j < 8; ++j) {
      const float4 xv = ((const float4*)(xs + (w * 8 + j) * IN_DIM))[i4];
#pragma unroll
      for (int k = 0; k < KF; ++k) {
        acc[j][k] = fmaf(xv.x, wv[k][0], acc[j][k]);
        acc[j][k] = fmaf(xv.y, wv[k][1], acc[j][k]);
        acc[j][k] = fmaf(xv.z, wv[k][2], acc[j][k]);
        acc[j][k] = fmaf(xv.w, wv[k][3], acc[j][k]);
      }
    }
  }

  float dmax[KF];
#pragma unroll
  for (int k = 0; k < KF; ++k) dmax[k] = 0.f;

#pragma unroll
  for (int j = 0; j < 8; ++j) {
    const int node = n0 + w * 8 + j;
#pragma unroll
    for (int k = 0; k < KF; ++k) {
      float z = fmaxf(acc[j][k], 0.f);
      float s = z * z;
#pragma unroll
      for (int d = 1; d < 64; d <<= 1) s += __shfl_xor(s, d, 64);
      const float zn = z / fmaxf(sqrtf(s), 1e-12f);
      if (node < N_NODES)
        out[OFF_Z + (size_t)node * (KF * HID) + k * HID + lane] = zn;
      dmax[k] = fmaxf(dmax[k], zn);
    }
  }

#pragma unroll
  for (int k = 0; k < KF; ++k) dred[w][k][lane] = dmax[k];
  __syncthreads();
  {
    const int k = tid >> 6;
    const float m = fmaxf(fmaxf(dred[0][k][lane], dred[1][k][lane]),
                          fmaxf(dred[2][k][lane], dred[3][k][lane]));
    atomicMax((unsigned int*)(out + OFF_DISEN + tid), __float_as_uint(m));
  }
}

// ---------------------------------------------------------------------------
// Kernel 2 (unchanged from r3): P/Q in bf16.
// ---------------------------------------------------------------------------
__global__ __launch_bounds__(256) void pq_kernel(
    const float* __restrict__ Z, const float* __restrict__ W1,
    const float* __restrict__ b1, unsigned short* __restrict__ P,
    unsigned short* __restrict__ Q) {
  __shared__ __align__(16) float zt[16 * HID];
  const int tid = threadIdx.x;
  const int lane = tid & 63;
  const int w = tid >> 6;

  float ws[HID], wd[HID];
#pragma unroll
  for (int h = 0; h < HID; ++h) {
    ws[h] = W1[h * EXP_HID + lane];
    wd[h] = W1[(HID + h) * EXP_HID + lane];
  }
  const float bb = b1[lane];

  const int rpb = NROWS / gridDim.x;
  const int base = blockIdx.x * rpb;
  for (int t = 0; t < rpb; t += 16) {
    __syncthreads();
    ((float4*)zt)[tid] = ((const float4*)(Z + (size_t)(base + t) * HID))[tid];
    __syncthreads();
#pragma unroll
    for (int r = 0; r < 4; ++r) {
      const int row = w * 4 + r;
      float accP = bb, accQ = 0.f;
      const float4* z4 = (const float4*)(zt + row * HID);
#pragma unroll
      for (int h4 = 0; h4 < 16; ++h4) {
        const float4 z = z4[h4];
        accP = fmaf(z.x, ws[h4 * 4 + 0], accP);
        accQ = fmaf(z.x, wd[h4 * 4 + 0], accQ);
        accP = fmaf(z.y, ws[h4 * 4 + 1], accP);
        accQ = fmaf(z.y, wd[h4 * 4 + 1], accQ);
        accP = fmaf(z.z, ws[h4 * 4 + 2], accP);
        accQ = fmaf(z.z, wd[h4 * 4 + 2], accQ);
        accP = fmaf(z.w, ws[h4 * 4 + 3], accP);
        accQ = fmaf(z.w, wd[h4 * 4 + 3], accQ);
      }
      const size_t orow = (size_t)(base + t + row) * EXP_HID + lane;
      __hip_bfloat16 hp = __float2bfloat16(accP);   // RNE
      __hip_bfloat16 hq = __float2bfloat16(accQ);
      P[orow] = *(unsigned short*)&hp;
      Q[orow] = *(unsigned short*)&hq;
    }
  }
}

// ---------------------------------------------------------------------------
// Kernel 3 (v4): wave-cooperative gather. Wave owns 64 edges; per edge all
// 64 lanes load the full 512B P[src] / Q[dst] rows with ONE dwordx2 instr
// each (fully coalesced -> 8 64B sectors vs 64 scattered line-touches).
// Lane l holds elements (k=l>>4, o=(l&15)*4 ..+4); partial dot with its 4
// W2 coefs; 4-stage shfl_xor sum inside each 16-lane k-group; e_k staged in
// LDS; coalesced ehall/ehf writes at wave end. 4-deep software pipeline.
// ---------------------------------------------------------------------------
__global__ __launch_bounds__(256) void edge_kernel4(
    const int* __restrict__ ei, const float* __restrict__ W2,
    const float* __restrict__ b2, const unsigned short* __restrict__ P,
    const unsigned short* __restrict__ Q, float* __restrict__ ehf,
    float* __restrict__ ehall) {
  __shared__ float tile[4][KF][EPW];               // 4 KB
  const int tid = threadIdx.x;
  const int w = tid >> 6;
  const int lane = tid & 63;
  const int eb = blockIdx.x * 256 + w * EPW;       // this wave's 64 edges

  const int o0 = (lane & 15) * 4;                  // lane's 4 output channels
  const float w2a = W2[o0 + 0], w2b = W2[o0 + 1];
  const float w2c = W2[o0 + 2], w2d = W2[o0 + 3];
  const float bias2 = b2[0];

  const int srcl = ei[eb + lane];                  // coalesced
  const int dstl = ei[E_EDGES + eb + lane];
  const int loff = lane * 4;                       // element offset in row

  uint2 pv[4], qv[4];
#pragma unroll
  for (int d = 0; d < 4; ++d) {
    const int s = __shfl(srcl, d, 64);             // readlane -> SGPR base
    const int t = __shfl(dstl, d, 64);
    pv[d] = *(const uint2*)(P + (size_t)s * (KF * EXP_HID) + loff);
    qv[d] = *(const uint2*)(Q + (size_t)t * (KF * EXP_HID) + loff);
  }

#pragma unroll
  for (int i = 0; i < EPW; ++i) {
    const uint2 p = pv[i & 3];
    const uint2 q = qv[i & 3];
    if (i + 4 < EPW) {                             // static under full unroll
      const int s = __shfl(srcl, i + 4, 64);
      const int t = __shfl(dstl, i + 4, 64);
      pv[i & 3] = *(const uint2*)(P + (size_t)s * (KF * EXP_HID) + loff);
      qv[i & 3] = *(const uint2*)(Q + (size_t)t * (KF * EXP_HID) + loff);
    }
    // unpack 4 bf16 pairs (exact bit-ops)
    const float pa = __uint_as_float(p.x << 16);
    const float pb = __uint_as_float(p.x & 0xffff0000u);
    const float pc = __uint_as_float(p.y << 16);
    const float pd = __uint_as_float(p.y & 0xffff0000u);
    const float qa = __uint_as_float(q.x << 16);
    const float qb = __uint_as_float(q.x & 0xffff0000u);
    const float qc = __uint_as_float(q.y << 16);
    const float qd = __uint_as_float(q.y & 0xffff0000u);

    float s4 = fmaxf(pa + qa, 0.f) * w2a;
    s4 = fmaf(fmaxf(pb + qb, 0.f), w2b, s4);
    s4 = fmaf(fmaxf(pc + qc, 0.f), w2c, s4);
    s4 = fmaf(fmaxf(pd + qd, 0.f), w2d, s4);

    // sum the 16 lanes of this k-group (masks < 16 stay in-group)
    s4 += __shfl_xor(s4, 1, 64);
    s4 += __shfl_xor(s4, 2, 64);
    s4 += __shfl_xor(s4, 4, 64);
    s4 += __shfl_xor(s4, 8, 64);
    if ((lane & 15) == 0) tile[w][lane >> 4][i] = s4 + bias2;
  }
  __syncthreads();

  const float v0 = tile[w][0][lane];
  const float v1 = tile[w][1][lane];
  const float v2 = tile[w][2][lane];
  const float v3 = tile[w][3][lane];
  ehall[(size_t)0 * E_EDGES + eb + lane] = v0;     // coalesced per wave
  ehall[(size_t)1 * E_EDGES + eb + lane] = v1;
  ehall[(size_t)2 * E_EDGES + eb + lane] = v2;
  ehall[(size_t)3 * E_EDGES + eb + lane] = v3;
  ehf[eb + lane] = fmaxf(fmaxf(v0, v1), fmaxf(v2, v3));
}

// ---------------------------------------------------------------------------
extern "C" void kernel_launch(void* const* d_in, const int* in_sizes, int n_in,
                              void* d_out, int out_size, void* d_ws,
                              size_t ws_size, hipStream_t stream) {
  const float* x      = (const float*)d_in[0];
  const int*   ei     = (const int*)  d_in[1];
  const float* W_init = (const float*)d_in[2];
  const float* b_init = (const float*)d_in[3];
  const float* W1     = (const float*)d_in[4];
  const float* b1     = (const float*)d_in[5];
  const float* W2     = (const float*)d_in[6];
  const float* b2     = (const float*)d_in[7];
  float* out = (float*)d_out;

  unsigned short* P = (unsigned short*)d_ws;     // ws >= 51.2MB (verified)
  unsigned short* Q = P + PQ_ELEMS;

  disen_init_kernel<<<1, KF * HID, 0, stream>>>(out + OFF_DISEN);
  z_kernel2<<<(N_NODES + NPB3 - 1) / NPB3, 256, 0, stream>>>(
      x, W_init, b_init, out);
  pq_kernel<<<3125, 256, 0, stream>>>(out + OFF_Z, W1, b1, P, Q);
  edge_kernel4<<<E_EDGES / 256, 256, 0, stream>>>(
      ei, W2, b2, P, Q, out + OFF_EHF, out + OFF_EHALL);
}

// Round 7
// 249.452 us; speedup vs baseline: 1.9319x; 1.0064x over previous
//
#include <hip/hip_runtime.h>
#include <hip/hip_bf16.h>
#include <math.h>

#define N_NODES 50000
#define E_EDGES 800000
#define IN_DIM  128
#define HID     64
#define KF      4
#define EXP_HID 64

// d_out layout (float32, concatenated in return order):
//   disen_graph_emb (K*HID = 256) | Z (N*K*HID = 12,800,000) |
//   e_h_final (E = 800,000)       | e_h_all (K*E = 3,200,000)
#define OFF_DISEN 0
#define OFF_Z     (KF*HID)
#define OFF_EHF   (OFF_Z + N_NODES*KF*HID)
#define OFF_EHALL (OFF_EHF + E_EDGES)

#define NPB4 32                  // nodes per block (8 per wave)
#define NROWS (N_NODES * KF)     // 200000 (n,k) rows
#define PQ_ELEMS ((size_t)NROWS * EXP_HID)   // 12.8M elems each (bf16)
#define EPW 64                   // edges per wave in edge_kernel4

// ---------------------------------------------------------------------------
__global__ void disen_init_kernel(float* __restrict__ disen) {
  disen[threadIdx.x] = 0.f;
}

// ---------------------------------------------------------------------------
// Fused node-side kernel. 1563 blocks x 256 threads, 32 nodes/block.
// Phase A (r5 z structure, acc[8][4]=32 VGPR): Z = relu(x.W_init+b),
//   row-normalize, write Z to d_out, fold disen-max; park zn in LDS zt
//   (32 KB, aliased over the dead 16 KB x-stage buffer).
// Phase B (r3 pq structure; phase-A regs dead -> ws/wd fit): P/Q rows from
//   zt broadcasts x W1 columns in 128 VGPRs; store bf16.
// Phases have disjoint register live-ranges — this is what r4's failed
// fusion got wrong (it held both at once: 156 VGPR, 10.9% occupancy).
// ---------------------------------------------------------------------------
__global__ __launch_bounds__(256) void node_fused_kernel(
    const float* __restrict__ x, const float* __restrict__ W,
    const float* __restrict__ b, const float* __restrict__ W1,
    const float* __restrict__ b1, float* __restrict__ out,
    unsigned short* __restrict__ P, unsigned short* __restrict__ Q) {
  __shared__ __align__(16) float zt[NPB4 * KF * HID];  // 32 KB; rows (n*4+k)
  __shared__ float dred[4][KF][64];                    // 4 KB
  float* xs = zt;                                      // alias: phase A only
  const int tid = threadIdx.x;
  const int w = tid >> 6;
  const int lane = tid & 63;
  const int n0 = blockIdx.x * NPB4;

  // ---- phase A: stage 32 x-rows (clamped tail reads exact row N-1) ----
#pragma unroll
  for (int t = 0; t < 4; ++t) {
    const int idx = t * 256 + tid;
    const int row = idx >> 5;                          // 32 float4 per row
    const int col4 = idx & 31;
    const int nr = min(n0 + row, N_NODES - 1);
    ((float4*)xs)[idx] = ((const float4*)(x + (size_t)nr * IN_DIM))[col4];
  }
  __syncthreads();

  float acc[8][KF];
#pragma unroll
  for (int j = 0; j < 8; ++j)
#pragma unroll
    for (int k = 0; k < KF; ++k) acc[j][k] = b[k * HID + lane];

  const float* wp = W + lane;                          // W[k][i][h=lane]
#pragma unroll 2
  for (int i4 = 0; i4 < IN_DIM / 4; ++i4) {
    float wv[KF][4];
#pragma unroll
    for (int k = 0; k < KF; ++k)
#pragma unroll
      for (int i = 0; i < 4; ++i)
        wv[k][i] = wp[(k * IN_DIM + i4 * 4 + i) * HID];    // coalesced, L2
#pragma unroll
    for (int j = 0; j < 8; ++j) {
      const float4 xv = ((const float4*)(xs + (w * 8 + j) * IN_DIM))[i4];
#pragma unroll
      for (int k = 0; k < KF; ++k) {
        acc[j][k] = fmaf(xv.x, wv[k][0], acc[j][k]);
        acc[j][k] = fmaf(xv.y, wv[k][1], acc[j][k]);
        acc[j][k] = fmaf(xv.z, wv[k][2], acc[j][k]);
        acc[j][k] = fmaf(xv.w, wv[k][3], acc[j][k]);
      }
    }
  }
  __syncthreads();   // all waves done reading xs; zt overwrite is now safe

  // ---- normalize, write Z + zt, fold disen-max ----
  float dmax[KF];
#pragma unroll
  for (int k = 0; k < KF; ++k) dmax[k] = 0.f;

#pragma unroll
  for (int j = 0; j < 8; ++j) {
    const int node = n0 + w * 8 + j;
#pragma unroll
    for (int k = 0; k < KF; ++k) {
      float z = fmaxf(acc[j][k], 0.f);
      float s = z * z;
#pragma unroll
      for (int d = 1; d < 64; d <<= 1) s += __shfl_xor(s, d, 64);
      const float zn = z / fmaxf(sqrtf(s), 1e-12f);
      if (node < N_NODES)
        out[OFF_Z + (size_t)node * (KF * HID) + k * HID + lane] = zn;
      zt[((w * 8 + j) * KF + k) * HID + lane] = zn;    // row = n_in_blk*4+k
      dmax[k] = fmaxf(dmax[k], zn);   // clamped rows duplicate row N-1: ok
    }
  }
#pragma unroll
  for (int k = 0; k < KF; ++k) dred[w][k][lane] = dmax[k];
  __syncthreads();   // zt + dred ready

  {
    const int k = tid >> 6;
    const float m = fmaxf(fmaxf(dred[0][k][lane], dred[1][k][lane]),
                          fmaxf(dred[2][k][lane], dred[3][k][lane]));
    // Z >= 0: uint-punned atomicMax is exact & order-independent
    atomicMax((unsigned int*)(out + OFF_DISEN + tid), __float_as_uint(m));
  }

  // ---- phase B: P/Q from zt (phase-A registers are dead here) ----
  float ws[HID], wd[HID];
#pragma unroll
  for (int h = 0; h < HID; ++h) {
    ws[h] = W1[h * EXP_HID + lane];                    // coalesced
    wd[h] = W1[(HID + h) * EXP_HID + lane];
  }
  const float bb = b1[lane];
  const size_t growbase = (size_t)blockIdx.x * (NPB4 * KF);

  for (int r = 0; r < 32; ++r) {                       // wave w: rows w*32+r
    const int row = w * 32 + r;
    float accP = bb, accQ = 0.f;
    const float4* z4 = (const float4*)(zt + row * HID);
#pragma unroll
    for (int h4 = 0; h4 < 16; ++h4) {
      const float4 z = z4[h4];                         // uniform broadcast
      accP = fmaf(z.x, ws[h4 * 4 + 0], accP);
      accQ = fmaf(z.x, wd[h4 * 4 + 0], accQ);
      accP = fmaf(z.y, ws[h4 * 4 + 1], accP);
      accQ = fmaf(z.y, wd[h4 * 4 + 1], accQ);
      accP = fmaf(z.z, ws[h4 * 4 + 2], accP);
      accQ = fmaf(z.z, wd[h4 * 4 + 2], accQ);
      accP = fmaf(z.w, ws[h4 * 4 + 3], accP);
      accQ = fmaf(z.w, wd[h4 * 4 + 3], accQ);
    }
    const size_t grow = growbase + row;
    if (grow < NROWS) {
      __hip_bfloat16 hp = __float2bfloat16(accP);      // RNE
      __hip_bfloat16 hq = __float2bfloat16(accQ);
      P[grow * EXP_HID + lane] = *(unsigned short*)&hp;
      Q[grow * EXP_HID + lane] = *(unsigned short*)&hq;
    }
  }
}

// ---------------------------------------------------------------------------
// Edge kernel (v4 + padded tile): wave-cooperative gather, 64 edges/wave.
// Per edge all 64 lanes load the full 512B P[src]/Q[dst] rows with one
// dwordx2 each (fully coalesced). tile padded to EPW+1... (k-stride 65)
// to kill the 4-way bank conflict seen in r6 (1.6M conflict cycles).
// ---------------------------------------------------------------------------
__global__ __launch_bounds__(256) void edge_kernel4(
    const int* __restrict__ ei, const float* __restrict__ W2,
    const float* __restrict__ b2, const unsigned short* __restrict__ P,
    const unsigned short* __restrict__ Q, float* __restrict__ ehf,
    float* __restrict__ ehall) {
  __shared__ float tile[4][KF][EPW + 1];           // pad: k-stride 65
  const int tid = threadIdx.x;
  const int w = tid >> 6;
  const int lane = tid & 63;
  const int eb = blockIdx.x * 256 + w * EPW;       // this wave's 64 edges

  const int o0 = (lane & 15) * 4;                  // lane's 4 output channels
  const float w2a = W2[o0 + 0], w2b = W2[o0 + 1];
  const float w2c = W2[o0 + 2], w2d = W2[o0 + 3];
  const float bias2 = b2[0];

  const int srcl = ei[eb + lane];                  // coalesced
  const int dstl = ei[E_EDGES + eb + lane];
  const int loff = lane * 4;                       // element offset in row

  uint2 pv[4], qv[4];
#pragma unroll
  for (int d = 0; d < 4; ++d) {
    const int s = __shfl(srcl, d, 64);             // readlane -> SGPR base
    const int t = __shfl(dstl, d, 64);
    pv[d] = *(const uint2*)(P + (size_t)s * (KF * EXP_HID) + loff);
    qv[d] = *(const uint2*)(Q + (size_t)t * (KF * EXP_HID) + loff);
  }

#pragma unroll
  for (int i = 0; i < EPW; ++i) {
    const uint2 p = pv[i & 3];
    const uint2 q = qv[i & 3];
    if (i + 4 < EPW) {                             // static under full unroll
      const int s = __shfl(srcl, i + 4, 64);
      const int t = __shfl(dstl, i + 4, 64);
      pv[i & 3] = *(const uint2*)(P + (size_t)s * (KF * EXP_HID) + loff);
      qv[i & 3] = *(const uint2*)(Q + (size_t)t * (KF * EXP_HID) + loff);
    }
    // unpack 4 bf16 pairs (exact bit-ops)
    const float pa = __uint_as_float(p.x << 16);
    const float pb = __uint_as_float(p.x & 0xffff0000u);
    const float pc = __uint_as_float(p.y << 16);
    const float pd = __uint_as_float(p.y & 0xffff0000u);
    const float qa = __uint_as_float(q.x << 16);
    const float qb = __uint_as_float(q.x & 0xffff0000u);
    const float qc = __uint_as_float(q.y << 16);
    const float qd = __uint_as_float(q.y & 0xffff0000u);

    float s4 = fmaxf(pa + qa, 0.f) * w2a;
    s4 = fmaf(fmaxf(pb + qb, 0.f), w2b, s4);
    s4 = fmaf(fmaxf(pc + qc, 0.f), w2c, s4);
    s4 = fmaf(fmaxf(pd + qd, 0.f), w2d, s4);

    // sum the 16 lanes of this k-group (masks < 16 stay in-group)
    s4 += __shfl_xor(s4, 1, 64);
    s4 += __shfl_xor(s4, 2, 64);
    s4 += __shfl_xor(s4, 4, 64);
    s4 += __shfl_xor(s4, 8, 64);
    if ((lane & 15) == 0) tile[w][lane >> 4][i] = s4 + bias2;
  }
  __syncthreads();

  const float v0 = tile[w][0][lane];
  const float v1 = tile[w][1][lane];
  const float v2 = tile[w][2][lane];
  const float v3 = tile[w][3][lane];
  ehall[(size_t)0 * E_EDGES + eb + lane] = v0;     // coalesced per wave
  ehall[(size_t)1 * E_EDGES + eb + lane] = v1;
  ehall[(size_t)2 * E_EDGES + eb + lane] = v2;
  ehall[(size_t)3 * E_EDGES + eb + lane] = v3;
  ehf[eb + lane] = fmaxf(fmaxf(v0, v1), fmaxf(v2, v3));
}

// ---------------------------------------------------------------------------
extern "C" void kernel_launch(void* const* d_in, const int* in_sizes, int n_in,
                              void* d_out, int out_size, void* d_ws,
                              size_t ws_size, hipStream_t stream) {
  const float* x      = (const float*)d_in[0];
  const int*   ei     = (const int*)  d_in[1];
  const float* W_init = (const float*)d_in[2];
  const float* b_init = (const float*)d_in[3];
  const float* W1     = (const float*)d_in[4];
  const float* b1     = (const float*)d_in[5];
  const float* W2     = (const float*)d_in[6];
  const float* b2     = (const float*)d_in[7];
  float* out = (float*)d_out;

  unsigned short* P = (unsigned short*)d_ws;     // ws >= 51.2MB (verified)
  unsigned short* Q = P + PQ_ELEMS;

  disen_init_kernel<<<1, KF * HID, 0, stream>>>(out + OFF_DISEN);
  node_fused_kernel<<<(N_NODES + NPB4 - 1) / NPB4, 256, 0, stream>>>(
      x, W_init, b_init, W1, b1, out, P, Q);
  edge_kernel4<<<E_EDGES / 256, 256, 0, stream>>>(
      ei, W2, b2, P, Q, out + OFF_EHF, out + OFF_EHALL);
}